// Round 3
// 445.123 us; speedup vs baseline: 1.0032x; 1.0032x over previous
//
#include <hip/hip_runtime.h>
#include <hip/hip_fp16.h>

#define NNODES 100000
#define NPAD   100032            // 64*1563
#define NEDGES 1600000
#define NBLK_GEMM (NPAD / 64)    // 1563

#define BKT   512                // nodes per bucket
#define NBKT  ((NNODES + BKT - 1) / BKT)   // 196
#define CAP   10240              // real-edge slab capacity (mean 8192)
#define PCAP  18432              // padded slab capacity (CAP + 512*16)
#define EPB   2048               // edges per block, pass A
#define NBLK_A ((NEDGES + EPB - 1) / EPB)

typedef _Float16 half8 __attribute__((ext_vector_type(8)));
typedef float floatx4 __attribute__((ext_vector_type(4)));
typedef int int4v __attribute__((ext_vector_type(4)));
typedef int int2v __attribute__((ext_vector_type(2)));

// ---------------- CSR pass A (verbatim R6) ----------------

__global__ __launch_bounds__(256) void k_binA(const int* __restrict__ src, const int* __restrict__ dst,
                                              int* __restrict__ gcur, unsigned* __restrict__ pairs) {
    __shared__ int cnt[NBKT];
    __shared__ int cur[NBKT];
    int t = threadIdx.x;
    if (t < NBKT) cnt[t] = 0;
    __syncthreads();
    int e0 = blockIdx.x * EPB;
    for (int i = t; i < EPB; i += 256) {
        int e = e0 + i;
        if (e < NEDGES) atomicAdd(&cnt[dst[e] >> 9], 1);
    }
    __syncthreads();
    if (t < NBKT) {
        int c = cnt[t];
        cur[t] = (c > 0) ? atomicAdd(&gcur[t], c) : 0;
    }
    __syncthreads();
    for (int i = t; i < EPB; i += 256) {
        int e = e0 + i;
        if (e < NEDGES) {
            int d = dst[e];
            int b = d >> 9;
            int pos = atomicAdd(&cur[b], 1);
            pairs[b * CAP + pos] = (unsigned)src[e] | ((unsigned)(d & 511) << 20);
        }
    }
}

// ---------------- CSR pass B with 16-padding ----------------
// per-bucket slab of PCAP edge slots at base b*PCAP; each node's edges padded
// to a multiple of 16 with sentinel NNODES (a zeroed feature row).
__global__ __launch_bounds__(512) void k_binB(const unsigned* __restrict__ pairs,
                                              const int* __restrict__ gcnt,
                                              int* __restrict__ row_beg, int* __restrict__ row_end,
                                              float* __restrict__ deg_inv,
                                              int* __restrict__ edge_src) {
    __shared__ int hist[BKT];
    __shared__ int sc[BKT];
    int b = blockIdx.x;
    int t = threadIdx.x;
    int n = gcnt[b];
    int base = b * PCAP;
    const unsigned* pp = pairs + (size_t)b * CAP;
    hist[t] = 0;
    __syncthreads();
    for (int i = t; i < n; i += 512) atomicAdd(&hist[pp[i] >> 20], 1);
    __syncthreads();
    int v = hist[t];                       // real degree of node b*512+t
    int pdeg = (v + 15) & ~15;             // padded to multiple of 16
    sc[t] = pdeg;
    __syncthreads();
#pragma unroll
    for (int off = 1; off < 512; off <<= 1) {
        int u = (t >= off) ? sc[t - off] : 0;
        __syncthreads();
        sc[t] += u;
        __syncthreads();
    }
    int pref = sc[t] - pdeg;               // exclusive prefix of padded degs
    int node = b * BKT + t;
    if (node < NNODES) {
        row_beg[node] = base + pref;
        row_end[node] = base + pref + pdeg;
        deg_inv[node] = 1.0f / fmaxf((float)v, 1.0f);
    }
    // sentinel-fill the padding slots
    for (int i = v; i < pdeg; ++i) edge_src[base + pref + i] = NNODES;
    __syncthreads();
    hist[t] = pref;                        // hist -> scatter cursor
    __syncthreads();
    for (int i = t; i < n; i += 512) {
        unsigned p = pp[i];
        int pos = atomicAdd(&hist[p >> 20], 1);
        edge_src[base + pos] = (int)(p & 0xFFFFF);
    }
}

// ---------------- fused prep: f2h + 3x wshuf (verbatim R6) -------------------
template <int C>
__device__ inline void wshuf_one(const float* __restrict__ Ws, const float* __restrict__ Wn,
                                 __half* __restrict__ Wb, int t) {
    constexpr int NCT = 2 * C / 16;
    int lane  = t & 63;
    int ctile = (t >> 6) % NCT;
    int kstep = t / (64 * NCT);
    int n  = ctile * 16 + (lane & 15);
    int k0 = kstep * 32 + (lane >> 4) * 8;
    half8 w8;
#pragma unroll
    for (int j = 0; j < 8; ++j) {
        int k = k0 + j;
        float w = (n < C) ? Ws[k * C + n] : Wn[k * C + (n - C)];
        w8[j] = (_Float16)w;
    }
    ((half8*)Wb)[t] = w8;
}

#define F2H_BLK 12500   // NNODES*128 floats = 3.2M float4 / 256

__global__ __launch_bounds__(256) void k_prep(const float* __restrict__ x, __half* __restrict__ x16,
                                              const float* __restrict__ Ws0, const float* __restrict__ Wn0, __half* __restrict__ Wb0,
                                              const float* __restrict__ Ws1, const float* __restrict__ Wn1, __half* __restrict__ Wb1,
                                              const float* __restrict__ Ws2, const float* __restrict__ Wn2, __half* __restrict__ Wb2) {
    int blk = blockIdx.x;
    if (blk < F2H_BLK) {
        int i = blk * 256 + threadIdx.x;
        float4 v = ((const float4*)x)[i];
        __half2* o = (__half2*)(x16 + (size_t)i * 4);
        o[0] = __floats2half2_rn(v.x, v.y);
        o[1] = __floats2half2_rn(v.z, v.w);
    } else if (blk < F2H_BLK + 16) {
        wshuf_one<128>(Ws0, Wn0, Wb0, (blk - F2H_BLK) * 256 + threadIdx.x);
    } else if (blk < F2H_BLK + 32) {
        wshuf_one<128>(Ws1, Wn1, Wb1, (blk - F2H_BLK - 16) * 256 + threadIdx.x);
    } else {
        wshuf_one<64>(Ws2, Wn2, Wb2, (blk - F2H_BLK - 32) * 256 + threadIdx.x);
    }
}

// ---------------- MFMA GEMM (R6 + zeroed zn sentinel row) --------------------
template <int C, bool ZS32>
__global__ __launch_bounds__(256) void k_gemm2(const __half* __restrict__ A,
                                               const __half* __restrict__ Wb,
                                               const float* __restrict__ bias,
                                               void* __restrict__ zs,
                                               __half* __restrict__ zn) {
    constexpr int NCT = 2 * C / 16;
    int lane = threadIdx.x & 63;
    int wave = threadIdx.x >> 6;
    int row0 = blockIdx.x * 64 + wave * 16;
    int m = lane & 15, quad = lane >> 4;
    const half8* Aq = (const half8*)(A + (size_t)(row0 + m) * 128 + quad * 8);
    const half8* Bq = (const half8*)Wb;

    floatx4 acc[NCT];
#pragma unroll
    for (int c = 0; c < NCT; ++c) acc[c] = floatx4{0.f, 0.f, 0.f, 0.f};

#pragma unroll
    for (int ks = 0; ks < 4; ++ks) {
        half8 a = Aq[ks * 4];
#pragma unroll
        for (int c = 0; c < NCT; ++c) {
            half8 b = Bq[(size_t)(ks * NCT + c) * 64 + lane];
            acc[c] = __builtin_amdgcn_mfma_f32_16x16x32_f16(a, b, acc[c], 0, 0, 0);
        }
    }

#pragma unroll
    for (int c = 0; c < NCT; ++c) {
        bool is_self = (c < NCT / 2);
        int col = (is_self ? c : c - NCT / 2) * 16 + m;
        float bv = is_self ? bias[col] : 0.f;
#pragma unroll
        for (int r = 0; r < 4; ++r) {
            int row = row0 + quad * 4 + r;
            float v = acc[c][r] + bv;
            if (is_self) {
                if (row < NNODES) {
                    if (ZS32) ((float*)zs)[(size_t)row * C + col] = v;
                    else      ((__half*)zs)[(size_t)row * C + col] = __float2half(v);
                }
            } else {
                // zn gets a zeroed sentinel row at index NNODES (gather padding)
                if (row < NNODES)       zn[(size_t)row * C + col] = __float2half(v);
                else if (row == NNODES) zn[(size_t)row * C + col] = __float2half(0.f);
            }
        }
    }
}

// ---------------- gather-add, batch-only (padded CSR) ------------------------
// Every node's edge count is a multiple of 16 = NSUB*UNR.
// R7: (1) contiguous slot->subgroup map so each lane grabs its UNR edge
// indices with ONE int4/int2 load; (2) fp16 packed accumulation (v_pk_add_f16,
// 4x fewer VALU ops than cvt+fma; <= ceil(deg/16)-1 extra fp16 rounds per
// accumulator, exact for deg<=16); (3) non-temporal hints on the streaming
// arrays (edge_src, zs, out) so they don't evict the zn gather set from L2.
template <int C, bool RELU, bool ZS32>
__global__ __launch_bounds__(256) void k_aggadd(const __half* __restrict__ zn,
                                                const void* __restrict__ zs,
                                                const int* __restrict__ row_beg,
                                                const int* __restrict__ row_end,
                                                const int* __restrict__ edge_src,
                                                const float* __restrict__ deg_inv,
                                                void* __restrict__ outv) {
    constexpr int LPR  = C / 8;            // half8 chunks per row (16 or 8)
    constexpr int NSUB = 64 / LPR;         // 4 (C=128) or 8 (C=64)
    constexpr int UNR  = 16 / NSUB;        // 4 or 2 -> batch = 16 edges
    int node = blockIdx.x * 4 + (threadIdx.x >> 6);
    int lane = threadIdx.x & 63;
    int su = lane / LPR;
    int lr = lane % LPR;
    int beg = row_beg[node];
    int end = row_end[node];
    const half8* zb = (const half8*)zn;

    half8 a[UNR];
#pragma unroll
    for (int u = 0; u < UNR; ++u)
#pragma unroll
        for (int j = 0; j < 8; ++j) a[u][j] = (_Float16)0.f;

    for (int p = beg; p < end; p += 16) {
        int idx[UNR];
        if constexpr (UNR == 4) {
            int4v i4 = __builtin_nontemporal_load((const int4v*)(edge_src + p) + su);
            idx[0] = i4.x; idx[1] = i4.y; idx[2] = i4.z; idx[3] = i4.w;
        } else {
            int2v i2 = __builtin_nontemporal_load((const int2v*)(edge_src + p) + su);
            idx[0] = i2.x; idx[1] = i2.y;
        }
        half8 v[UNR];
#pragma unroll
        for (int u = 0; u < UNR; ++u) v[u] = zb[(size_t)idx[u] * LPR + lr];
#pragma unroll
        for (int u = 0; u < UNR; ++u) a[u] += v[u];   // v_pk_add_f16 x4
    }

    // combine the UNR fp16 accumulators in f32, then cross-subgroup reduce
    float s[8];
#pragma unroll
    for (int j = 0; j < 8; ++j) {
        float t = (float)a[0][j];
#pragma unroll
        for (int u = 1; u < UNR; ++u) t += (float)a[u][j];
        s[j] = t;
    }
#pragma unroll
    for (int off = 32; off >= LPR; off >>= 1) {
#pragma unroll
        for (int j = 0; j < 8; ++j) s[j] += __shfl_xor(s[j], off, 64);
    }

    if (su == 0) {
        float di = deg_inv[node];
        float o[8];
        if (ZS32) {
            // row = C floats = C/4 floatx4 per node
            const floatx4* zp = (const floatx4*)zs + (size_t)node * (C / 4) + lr * 2;
            floatx4 z0 = __builtin_nontemporal_load(zp);
            floatx4 z1 = __builtin_nontemporal_load(zp + 1);
            o[0] = z0.x + s[0] * di; o[1] = z0.y + s[1] * di;
            o[2] = z0.z + s[2] * di; o[3] = z0.w + s[3] * di;
            o[4] = z1.x + s[4] * di; o[5] = z1.y + s[5] * di;
            o[6] = z1.z + s[6] * di; o[7] = z1.w + s[7] * di;
        } else {
            half8 z = __builtin_nontemporal_load((const half8*)zs + (size_t)node * LPR + lr);
#pragma unroll
            for (int j = 0; j < 8; ++j) o[j] = (float)z[j] + s[j] * di;
        }
        if (RELU) {
#pragma unroll
            for (int j = 0; j < 8; ++j) o[j] = fmaxf(o[j], 0.f);
        }
        if (ZS32) {
            floatx4* op = (floatx4*)outv + (size_t)node * (C / 4) + lr * 2;
            __builtin_nontemporal_store(floatx4{o[0], o[1], o[2], o[3]}, op);
            __builtin_nontemporal_store(floatx4{o[4], o[5], o[6], o[7]}, op + 1);
        } else {
            half8 h;
#pragma unroll
            for (int j = 0; j < 8; ++j) h[j] = (_Float16)o[j];
            __builtin_nontemporal_store(h, (half8*)outv + (size_t)node * LPR + lr);
        }
    }
}

// ---------------- launch ----------------

extern "C" void kernel_launch(void* const* d_in, const int* in_sizes, int n_in,
                              void* d_out, int out_size, void* d_ws, size_t ws_size,
                              hipStream_t stream) {
    const float* x   = (const float*)d_in[0];
    const int*   src = (const int*)d_in[1];
    const int*   dst = (const int*)d_in[2];
    const float* Ws0 = (const float*)d_in[3];
    const float* Wn0 = (const float*)d_in[4];
    const float* b0  = (const float*)d_in[5];
    const float* Ws1 = (const float*)d_in[6];
    const float* Wn1 = (const float*)d_in[7];
    const float* b1  = (const float*)d_in[8];
    const float* Ws2 = (const float*)d_in[9];
    const float* Wn2 = (const float*)d_in[10];
    const float* b2  = (const float*)d_in[11];
    float* out = (float*)d_out;

    char* ws = (char*)d_ws;
    size_t off = 0;
    auto alloc = [&](size_t bytes) -> void* {
        off = (off + 255) & ~(size_t)255;
        void* p = ws + off;
        off += bytes;
        return p;
    };
    int*      row_beg  = (int*)alloc((size_t)NNODES * 4);
    int*      row_end  = (int*)alloc((size_t)NNODES * 4);
    float*    deg_inv  = (float*)alloc((size_t)NNODES * 4);
    int*      edge_src = (int*)alloc((size_t)NBKT * PCAP * 4);
    int*      gcur     = (int*)alloc((size_t)NBKT * 4);
    unsigned* pairs    = (unsigned*)alloc((size_t)NBKT * CAP * 4);
    __half*   x16      = (__half*)alloc((size_t)NPAD * 128 * 2);
    __half*   h1       = (__half*)alloc((size_t)NPAD * 128 * 2);
    __half*   h2       = (__half*)alloc((size_t)NPAD * 128 * 2);
    __half*   zs16     = (__half*)alloc((size_t)NNODES * 128 * 2);
    __half*   zn128    = (__half*)alloc((size_t)NPAD * 128 * 2);
    float*    zs32     = (float*)alloc((size_t)NNODES * 64 * 4);
    __half*   zn64     = (__half*)alloc((size_t)NPAD * 64 * 2);
    __half*   Wb0      = (__half*)alloc((size_t)4 * 16 * 64 * 8 * 2);
    __half*   Wb1      = (__half*)alloc((size_t)4 * 16 * 64 * 8 * 2);
    __half*   Wb2      = (__half*)alloc((size_t)4 * 8 * 64 * 8 * 2);
    (void)ws_size; (void)n_in; (void)in_sizes; (void)out_size;

    // CSR build (bucketed, padded)
    hipMemsetAsync(gcur, 0, (size_t)NBKT * 4, stream);
    k_binA<<<NBLK_A, 256, 0, stream>>>(src, dst, gcur, pairs);
    k_binB<<<NBKT, 512, 0, stream>>>(pairs, gcur, row_beg, row_end, deg_inv, edge_src);

    // prep: f2h + 3x wshuf fused
    k_prep<<<F2H_BLK + 40, 256, 0, stream>>>(x, x16, Ws0, Wn0, Wb0, Ws1, Wn1, Wb1, Ws2, Wn2, Wb2);

    // layer 0: x16 -> h1
    k_gemm2<128, false><<<NBLK_GEMM, 256, 0, stream>>>(x16, Wb0, b0, zs16, zn128);
    k_aggadd<128, true, false><<<NNODES / 4, 256, 0, stream>>>(zn128, zs16, row_beg, row_end, edge_src, deg_inv, h1);
    // layer 1: h1 -> h2
    k_gemm2<128, false><<<NBLK_GEMM, 256, 0, stream>>>(h1, Wb1, b1, zs16, zn128);
    k_aggadd<128, true, false><<<NNODES / 4, 256, 0, stream>>>(zn128, zs16, row_beg, row_end, edge_src, deg_inv, h2);
    // layer 2: h2 -> out (fp32), gather width 64
    k_gemm2<64, true><<<NBLK_GEMM, 256, 0, stream>>>(h2, Wb2, b2, zs32, zn64);
    k_aggadd<64, false, true><<<NNODES / 4, 256, 0, stream>>>(zn64, zs32, row_beg, row_end, edge_src, deg_inv, out);
}

// Round 4
// 435.262 us; speedup vs baseline: 1.0259x; 1.0227x over previous
//
#include <hip/hip_runtime.h>
#include <hip/hip_fp16.h>

#define NNODES 100000
#define NPAD   100032            // 64*1563
#define NEDGES 1600000
#define NBLK_GEMM (NPAD / 64)    // 1563

#define BKT   512                // nodes per bucket
#define NBKT  ((NNODES + BKT - 1) / BKT)   // 196
#define CAP   10240              // real-edge slab capacity (mean 8192)
#define PCAP  18432              // padded slab capacity (CAP + 512*16)
#define EPB   2048               // edges per block, pass A
#define NBLK_A ((NEDGES + EPB - 1) / EPB)

typedef _Float16 half8 __attribute__((ext_vector_type(8)));
typedef float floatx4 __attribute__((ext_vector_type(4)));
typedef int int4v __attribute__((ext_vector_type(4)));

// ---------------- CSR pass A (verbatim) ----------------

__global__ __launch_bounds__(256) void k_binA(const int* __restrict__ src, const int* __restrict__ dst,
                                              int* __restrict__ gcur, unsigned* __restrict__ pairs) {
    __shared__ int cnt[NBKT];
    __shared__ int cur[NBKT];
    int t = threadIdx.x;
    if (t < NBKT) cnt[t] = 0;
    __syncthreads();
    int e0 = blockIdx.x * EPB;
    for (int i = t; i < EPB; i += 256) {
        int e = e0 + i;
        if (e < NEDGES) atomicAdd(&cnt[dst[e] >> 9], 1);
    }
    __syncthreads();
    if (t < NBKT) {
        int c = cnt[t];
        cur[t] = (c > 0) ? atomicAdd(&gcur[t], c) : 0;
    }
    __syncthreads();
    for (int i = t; i < EPB; i += 256) {
        int e = e0 + i;
        if (e < NEDGES) {
            int d = dst[e];
            int b = d >> 9;
            int pos = atomicAdd(&cur[b], 1);
            pairs[b * CAP + pos] = (unsigned)src[e] | ((unsigned)(d & 511) << 20);
        }
    }
}

// ---------------- CSR pass B with 16-padding + packed row_ptr ----------------
// row_ptr[node] = (slab offset of first edge) | (num 16-edge batches << 24).
// beg < 196*18432 = 3.6M < 2^24; nb <= ~4. One load instead of two in aggadd.
__global__ __launch_bounds__(512) void k_binB(const unsigned* __restrict__ pairs,
                                              const int* __restrict__ gcnt,
                                              int* __restrict__ row_ptr,
                                              float* __restrict__ deg_inv,
                                              int* __restrict__ edge_src) {
    __shared__ int hist[BKT];
    __shared__ int sc[BKT];
    int b = blockIdx.x;
    int t = threadIdx.x;
    int n = gcnt[b];
    int base = b * PCAP;
    const unsigned* pp = pairs + (size_t)b * CAP;
    hist[t] = 0;
    __syncthreads();
    for (int i = t; i < n; i += 512) atomicAdd(&hist[pp[i] >> 20], 1);
    __syncthreads();
    int v = hist[t];                       // real degree of node b*512+t
    int pdeg = (v + 15) & ~15;             // padded to multiple of 16
    sc[t] = pdeg;
    __syncthreads();
#pragma unroll
    for (int off = 1; off < 512; off <<= 1) {
        int u = (t >= off) ? sc[t - off] : 0;
        __syncthreads();
        sc[t] += u;
        __syncthreads();
    }
    int pref = sc[t] - pdeg;               // exclusive prefix of padded degs
    int node = b * BKT + t;
    if (node < NNODES) {
        row_ptr[node] = (base + pref) | ((pdeg >> 4) << 24);
        deg_inv[node] = 1.0f / fmaxf((float)v, 1.0f);
    }
    // sentinel-fill the padding slots
    for (int i = v; i < pdeg; ++i) edge_src[base + pref + i] = NNODES;
    __syncthreads();
    hist[t] = pref;                        // hist -> scatter cursor
    __syncthreads();
    for (int i = t; i < n; i += 512) {
        unsigned p = pp[i];
        int pos = atomicAdd(&hist[p >> 20], 1);
        edge_src[base + pos] = (int)(p & 0xFFFFF);
    }
}

// ---------------- fused prep: f2h + 3x wshuf (verbatim) ----------------------
template <int C>
__device__ inline void wshuf_one(const float* __restrict__ Ws, const float* __restrict__ Wn,
                                 __half* __restrict__ Wb, int t) {
    constexpr int NCT = 2 * C / 16;
    int lane  = t & 63;
    int ctile = (t >> 6) % NCT;
    int kstep = t / (64 * NCT);
    int n  = ctile * 16 + (lane & 15);
    int k0 = kstep * 32 + (lane >> 4) * 8;
    half8 w8;
#pragma unroll
    for (int j = 0; j < 8; ++j) {
        int k = k0 + j;
        float w = (n < C) ? Ws[k * C + n] : Wn[k * C + (n - C)];
        w8[j] = (_Float16)w;
    }
    ((half8*)Wb)[t] = w8;
}

#define F2H_BLK 12500   // NNODES*128 floats = 3.2M float4 / 256

__global__ __launch_bounds__(256) void k_prep(const float* __restrict__ x, __half* __restrict__ x16,
                                              const float* __restrict__ Ws0, const float* __restrict__ Wn0, __half* __restrict__ Wb0,
                                              const float* __restrict__ Ws1, const float* __restrict__ Wn1, __half* __restrict__ Wb1,
                                              const float* __restrict__ Ws2, const float* __restrict__ Wn2, __half* __restrict__ Wb2) {
    int blk = blockIdx.x;
    if (blk < F2H_BLK) {
        int i = blk * 256 + threadIdx.x;
        float4 v = ((const float4*)x)[i];
        __half2* o = (__half2*)(x16 + (size_t)i * 4);
        o[0] = __floats2half2_rn(v.x, v.y);
        o[1] = __floats2half2_rn(v.z, v.w);
    } else if (blk < F2H_BLK + 16) {
        wshuf_one<128>(Ws0, Wn0, Wb0, (blk - F2H_BLK) * 256 + threadIdx.x);
    } else if (blk < F2H_BLK + 32) {
        wshuf_one<128>(Ws1, Wn1, Wb1, (blk - F2H_BLK - 16) * 256 + threadIdx.x);
    } else {
        wshuf_one<64>(Ws2, Wn2, Wb2, (blk - F2H_BLK - 32) * 256 + threadIdx.x);
    }
}

// ---------------- MFMA GEMM (verbatim, zeroed zn sentinel row) ---------------
template <int C, bool ZS32>
__global__ __launch_bounds__(256) void k_gemm2(const __half* __restrict__ A,
                                               const __half* __restrict__ Wb,
                                               const float* __restrict__ bias,
                                               void* __restrict__ zs,
                                               __half* __restrict__ zn) {
    constexpr int NCT = 2 * C / 16;
    int lane = threadIdx.x & 63;
    int wave = threadIdx.x >> 6;
    int row0 = blockIdx.x * 64 + wave * 16;
    int m = lane & 15, quad = lane >> 4;
    const half8* Aq = (const half8*)(A + (size_t)(row0 + m) * 128 + quad * 8);
    const half8* Bq = (const half8*)Wb;

    floatx4 acc[NCT];
#pragma unroll
    for (int c = 0; c < NCT; ++c) acc[c] = floatx4{0.f, 0.f, 0.f, 0.f};

#pragma unroll
    for (int ks = 0; ks < 4; ++ks) {
        half8 a = Aq[ks * 4];
#pragma unroll
        for (int c = 0; c < NCT; ++c) {
            half8 b = Bq[(size_t)(ks * NCT + c) * 64 + lane];
            acc[c] = __builtin_amdgcn_mfma_f32_16x16x32_f16(a, b, acc[c], 0, 0, 0);
        }
    }

#pragma unroll
    for (int c = 0; c < NCT; ++c) {
        bool is_self = (c < NCT / 2);
        int col = (is_self ? c : c - NCT / 2) * 16 + m;
        float bv = is_self ? bias[col] : 0.f;
#pragma unroll
        for (int r = 0; r < 4; ++r) {
            int row = row0 + quad * 4 + r;
            float v = acc[c][r] + bv;
            if (is_self) {
                if (row < NNODES) {
                    if (ZS32) ((float*)zs)[(size_t)row * C + col] = v;
                    else      ((__half*)zs)[(size_t)row * C + col] = __float2half(v);
                }
            } else {
                // zn gets a zeroed sentinel row at index NNODES (gather padding)
                if (row < NNODES)       zn[(size_t)row * C + col] = __float2half(v);
                else if (row == NNODES) zn[(size_t)row * C + col] = __float2half(0.f);
            }
        }
    }
}

// ---------------- gather-add: subgroup-per-node, 16 gathers in flight --------
// R8: one LPR-lane subgroup owns one node (wave = NSUB nodes). The subgroup's
// lanes cover the full C-column row, so a 16-edge batch issues 16 independent
// row-gathers per lane -> 4x the memory-level parallelism of the old 1-node-
// per-wave scheme, and the cross-lane shuffle reduce disappears (each lane
// accumulates its own 8 columns via an fp16 pairwise tree, f32 across batches).
template <int C, bool RELU, bool ZS32>
__global__ __launch_bounds__(256) void k_aggadd(const __half* __restrict__ zn,
                                                const void* __restrict__ zs,
                                                const int* __restrict__ row_ptr,
                                                const int* __restrict__ edge_src,
                                                const float* __restrict__ deg_inv,
                                                void* __restrict__ outv) {
    constexpr int LPR  = C / 8;            // lanes per node-row: 16 (C=128) or 8
    constexpr int NSUB = 64 / LPR;         // nodes per wave: 4 or 8
    constexpr int NPB  = 4 * NSUB;         // nodes per block: 16 or 32
    int lane = threadIdx.x & 63;
    int su = lane / LPR;
    int lr = lane % LPR;
    int node = blockIdx.x * NPB + (threadIdx.x >> 6) * NSUB + su;
    unsigned rp = (unsigned)row_ptr[node];
    int beg = (int)(rp & 0xFFFFFFu << 0) & 0xFFFFFF;
    int nb  = (int)(rp >> 24);
    const half8* zb = (const half8*)zn;

    float s[8];
#pragma unroll
    for (int j = 0; j < 8; ++j) s[j] = 0.f;

    for (int b = 0; b < nb; ++b) {
        const int4v* ip = (const int4v*)(edge_src + beg + b * 16);
        int4v i0 = __builtin_nontemporal_load(ip);
        int4v i1 = __builtin_nontemporal_load(ip + 1);
        int4v i2 = __builtin_nontemporal_load(ip + 2);
        int4v i3 = __builtin_nontemporal_load(ip + 3);
        half8 v[16];
        v[0]  = zb[(size_t)i0.x * LPR + lr];
        v[1]  = zb[(size_t)i0.y * LPR + lr];
        v[2]  = zb[(size_t)i0.z * LPR + lr];
        v[3]  = zb[(size_t)i0.w * LPR + lr];
        v[4]  = zb[(size_t)i1.x * LPR + lr];
        v[5]  = zb[(size_t)i1.y * LPR + lr];
        v[6]  = zb[(size_t)i1.z * LPR + lr];
        v[7]  = zb[(size_t)i1.w * LPR + lr];
        v[8]  = zb[(size_t)i2.x * LPR + lr];
        v[9]  = zb[(size_t)i2.y * LPR + lr];
        v[10] = zb[(size_t)i2.z * LPR + lr];
        v[11] = zb[(size_t)i2.w * LPR + lr];
        v[12] = zb[(size_t)i3.x * LPR + lr];
        v[13] = zb[(size_t)i3.y * LPR + lr];
        v[14] = zb[(size_t)i3.z * LPR + lr];
        v[15] = zb[(size_t)i3.w * LPR + lr];
        // fp16 pairwise tree: 16 -> 1 (v_pk_add_f16)
#pragma unroll
        for (int st = 1; st < 16; st <<= 1)
#pragma unroll
            for (int e = 0; e < 16; e += 2 * st) v[e] += v[e + st];
#pragma unroll
        for (int j = 0; j < 8; ++j) s[j] += (float)v[0][j];
    }

    float di = deg_inv[node];
    float o[8];
    if (ZS32) {
        const floatx4* zp = (const floatx4*)zs + (size_t)node * (C / 4) + lr * 2;
        floatx4 z0 = __builtin_nontemporal_load(zp);
        floatx4 z1 = __builtin_nontemporal_load(zp + 1);
        o[0] = z0.x + s[0] * di; o[1] = z0.y + s[1] * di;
        o[2] = z0.z + s[2] * di; o[3] = z0.w + s[3] * di;
        o[4] = z1.x + s[4] * di; o[5] = z1.y + s[5] * di;
        o[6] = z1.z + s[6] * di; o[7] = z1.w + s[7] * di;
    } else {
        half8 z = __builtin_nontemporal_load((const half8*)zs + (size_t)node * LPR + lr);
#pragma unroll
        for (int j = 0; j < 8; ++j) o[j] = (float)z[j] + s[j] * di;
    }
    if (RELU) {
#pragma unroll
        for (int j = 0; j < 8; ++j) o[j] = fmaxf(o[j], 0.f);
    }
    if (ZS32) {
        floatx4* op = (floatx4*)outv + (size_t)node * (C / 4) + lr * 2;
        __builtin_nontemporal_store(floatx4{o[0], o[1], o[2], o[3]}, op);
        __builtin_nontemporal_store(floatx4{o[4], o[5], o[6], o[7]}, op + 1);
    } else {
        half8 h;
#pragma unroll
        for (int j = 0; j < 8; ++j) h[j] = (_Float16)o[j];
        __builtin_nontemporal_store(h, (half8*)outv + (size_t)node * LPR + lr);
    }
}

// ---------------- launch ----------------

extern "C" void kernel_launch(void* const* d_in, const int* in_sizes, int n_in,
                              void* d_out, int out_size, void* d_ws, size_t ws_size,
                              hipStream_t stream) {
    const float* x   = (const float*)d_in[0];
    const int*   src = (const int*)d_in[1];
    const int*   dst = (const int*)d_in[2];
    const float* Ws0 = (const float*)d_in[3];
    const float* Wn0 = (const float*)d_in[4];
    const float* b0  = (const float*)d_in[5];
    const float* Ws1 = (const float*)d_in[6];
    const float* Wn1 = (const float*)d_in[7];
    const float* b1  = (const float*)d_in[8];
    const float* Ws2 = (const float*)d_in[9];
    const float* Wn2 = (const float*)d_in[10];
    const float* b2  = (const float*)d_in[11];
    float* out = (float*)d_out;

    char* ws = (char*)d_ws;
    size_t off = 0;
    auto alloc = [&](size_t bytes) -> void* {
        off = (off + 255) & ~(size_t)255;
        void* p = ws + off;
        off += bytes;
        return p;
    };
    int*      row_ptr  = (int*)alloc((size_t)NNODES * 4);
    float*    deg_inv  = (float*)alloc((size_t)NNODES * 4);
    int*      edge_src = (int*)alloc((size_t)NBKT * PCAP * 4);
    int*      gcur     = (int*)alloc((size_t)NBKT * 4);
    unsigned* pairs    = (unsigned*)alloc((size_t)NBKT * CAP * 4);
    __half*   x16      = (__half*)alloc((size_t)NPAD * 128 * 2);
    __half*   h1       = (__half*)alloc((size_t)NPAD * 128 * 2);
    __half*   h2       = (__half*)alloc((size_t)NPAD * 128 * 2);
    __half*   zs16     = (__half*)alloc((size_t)NNODES * 128 * 2);
    __half*   zn128    = (__half*)alloc((size_t)NPAD * 128 * 2);
    float*    zs32     = (float*)alloc((size_t)NNODES * 64 * 4);
    __half*   zn64     = (__half*)alloc((size_t)NPAD * 64 * 2);
    __half*   Wb0      = (__half*)alloc((size_t)4 * 16 * 64 * 8 * 2);
    __half*   Wb1      = (__half*)alloc((size_t)4 * 16 * 64 * 8 * 2);
    __half*   Wb2      = (__half*)alloc((size_t)4 * 8 * 64 * 8 * 2);
    (void)ws_size; (void)n_in; (void)in_sizes; (void)out_size;

    // CSR build (bucketed, padded)
    hipMemsetAsync(gcur, 0, (size_t)NBKT * 4, stream);
    k_binA<<<NBLK_A, 256, 0, stream>>>(src, dst, gcur, pairs);
    k_binB<<<NBKT, 512, 0, stream>>>(pairs, gcur, row_ptr, deg_inv, edge_src);

    // prep: f2h + 3x wshuf fused
    k_prep<<<F2H_BLK + 40, 256, 0, stream>>>(x, x16, Ws0, Wn0, Wb0, Ws1, Wn1, Wb1, Ws2, Wn2, Wb2);

    // layer 0: x16 -> h1
    k_gemm2<128, false><<<NBLK_GEMM, 256, 0, stream>>>(x16, Wb0, b0, zs16, zn128);
    k_aggadd<128, true, false><<<NNODES / 16, 256, 0, stream>>>(zn128, zs16, row_ptr, edge_src, deg_inv, h1);
    // layer 1: h1 -> h2
    k_gemm2<128, false><<<NBLK_GEMM, 256, 0, stream>>>(h1, Wb1, b1, zs16, zn128);
    k_aggadd<128, true, false><<<NNODES / 16, 256, 0, stream>>>(zn128, zs16, row_ptr, edge_src, deg_inv, h2);
    // layer 2: h2 -> out (fp32), gather width 64
    k_gemm2<64, true><<<NBLK_GEMM, 256, 0, stream>>>(h2, Wb2, b2, zs32, zn64);
    k_aggadd<64, false, true><<<NNODES / 32, 256, 0, stream>>>(zn64, zs32, row_ptr, edge_src, deg_inv, out);
}

// Round 5
// 427.322 us; speedup vs baseline: 1.0450x; 1.0186x over previous
//
#include <hip/hip_runtime.h>
#include <hip/hip_fp16.h>

#define NNODES 100000
#define NPAD   100032            // 64*1563
#define NEDGES 1600000
#define NBLK_GEMM (NPAD / 64)    // 1563

#define BKT   512                // nodes per bucket
#define NBKT  ((NNODES + BKT - 1) / BKT)   // 196
#define CAP   10240              // real-edge slab capacity (mean 8192)
#define PCAP  18432              // padded slab capacity (CAP + 512*16)
#define EPB   2048               // edges per block, pass A
#define NBLK_A ((NEDGES + EPB - 1) / EPB)

typedef _Float16 half8 __attribute__((ext_vector_type(8)));
typedef float floatx4 __attribute__((ext_vector_type(4)));
typedef int int4v __attribute__((ext_vector_type(4)));

// ---------------- weight shuffle (f32 -> MFMA-B-layout f16) ------------------
template <int C>
__device__ inline void wshuf_one(const float* __restrict__ Ws, const float* __restrict__ Wn,
                                 __half* __restrict__ Wb, int t) {
    constexpr int NCT = 2 * C / 16;
    int lane  = t & 63;
    int ctile = (t >> 6) % NCT;
    int kstep = t / (64 * NCT);
    int n  = ctile * 16 + (lane & 15);
    int k0 = kstep * 32 + (lane >> 4) * 8;
    half8 w8;
#pragma unroll
    for (int j = 0; j < 8; ++j) {
        int k = k0 + j;
        float w = (n < C) ? Ws[k * C + n] : Wn[k * C + (n - C)];
        w8[j] = (_Float16)w;
    }
    ((half8*)Wb)[t] = w8;
}

// ---------------- CSR pass A + fused wshuf -----------------------------------
__global__ __launch_bounds__(256) void k_binA(const int* __restrict__ src, const int* __restrict__ dst,
                                              int* __restrict__ gcur, unsigned* __restrict__ pairs,
                                              const float* __restrict__ Ws0, const float* __restrict__ Wn0, __half* __restrict__ Wb0,
                                              const float* __restrict__ Ws1, const float* __restrict__ Wn1, __half* __restrict__ Wb1,
                                              const float* __restrict__ Ws2, const float* __restrict__ Wn2, __half* __restrict__ Wb2) {
    __shared__ int cnt[NBKT];
    __shared__ int cur[NBKT];
    if (blockIdx.x >= NBLK_A) {
        int wb = blockIdx.x - NBLK_A;
        if (wb < 16)      wshuf_one<128>(Ws0, Wn0, Wb0, wb * 256 + threadIdx.x);
        else if (wb < 32) wshuf_one<128>(Ws1, Wn1, Wb1, (wb - 16) * 256 + threadIdx.x);
        else              wshuf_one<64>(Ws2, Wn2, Wb2, (wb - 32) * 256 + threadIdx.x);
        return;
    }
    int t = threadIdx.x;
    if (t < NBKT) cnt[t] = 0;
    __syncthreads();
    int e0 = blockIdx.x * EPB;
    for (int i = t; i < EPB; i += 256) {
        int e = e0 + i;
        if (e < NEDGES) atomicAdd(&cnt[dst[e] >> 9], 1);
    }
    __syncthreads();
    if (t < NBKT) {
        int c = cnt[t];
        cur[t] = (c > 0) ? atomicAdd(&gcur[t], c) : 0;
    }
    __syncthreads();
    for (int i = t; i < EPB; i += 256) {
        int e = e0 + i;
        if (e < NEDGES) {
            int d = dst[e];
            int b = d >> 9;
            int pos = atomicAdd(&cur[b], 1);
            pairs[b * CAP + pos] = (unsigned)src[e] | ((unsigned)(d & 511) << 20);
        }
    }
}

// ---------------- CSR pass B with 16-padding + packed row_ptr ----------------
// row_ptr[node] = (slab offset of first edge) | (num 16-edge batches << 24).
__global__ __launch_bounds__(512) void k_binB(const unsigned* __restrict__ pairs,
                                              const int* __restrict__ gcnt,
                                              int* __restrict__ row_ptr,
                                              float* __restrict__ deg_inv,
                                              int* __restrict__ edge_src) {
    __shared__ int hist[BKT];
    __shared__ int sc[BKT];
    int b = blockIdx.x;
    int t = threadIdx.x;
    int n = gcnt[b];
    int base = b * PCAP;
    const unsigned* pp = pairs + (size_t)b * CAP;
    hist[t] = 0;
    __syncthreads();
    for (int i = t; i < n; i += 512) atomicAdd(&hist[pp[i] >> 20], 1);
    __syncthreads();
    int v = hist[t];                       // real degree of node b*512+t
    int pdeg = (v + 15) & ~15;             // padded to multiple of 16
    sc[t] = pdeg;
    __syncthreads();
#pragma unroll
    for (int off = 1; off < 512; off <<= 1) {
        int u = (t >= off) ? sc[t - off] : 0;
        __syncthreads();
        sc[t] += u;
        __syncthreads();
    }
    int pref = sc[t] - pdeg;               // exclusive prefix of padded degs
    int node = b * BKT + t;
    if (node < NNODES) {
        row_ptr[node] = (base + pref) | ((pdeg >> 4) << 24);
        deg_inv[node] = 1.0f / fmaxf((float)v, 1.0f);
    }
    // sentinel-fill the padding slots
    for (int i = v; i < pdeg; ++i) edge_src[base + pref + i] = NNODES;
    __syncthreads();
    hist[t] = pref;                        // hist -> scatter cursor
    __syncthreads();
    for (int i = t; i < n; i += 512) {
        unsigned p = pp[i];
        int pos = atomicAdd(&hist[p >> 20], 1);
        edge_src[base + pos] = (int)(p & 0xFFFFF);
    }
}

// ---------------- MFMA GEMM, LDS-staged coalesced epilogue -------------------
// R9: (1) AF32 variant reads f32 x directly (kills the f2h prep pass; row
// index clamped to stay in-bounds on the exact-size input); (2) epilogue
// stages acc into a per-wave LDS slab (no barrier needed: same-wave ds_write->
// ds_read, compiler inserts lgkmcnt) and writes zs/zn with half8/float4
// coalesced stores: 8 VMEM stores/lane instead of 64 scalar 2B stores.
template <int C, bool ZS32, bool AF32>
__global__ __launch_bounds__(256) void k_gemm2(const void* __restrict__ Av,
                                               const __half* __restrict__ Wb,
                                               const float* __restrict__ bias,
                                               void* __restrict__ zs,
                                               __half* __restrict__ zn) {
    constexpr int NCT = 2 * C / 16;
    int lane = threadIdx.x & 63;
    int wave = threadIdx.x >> 6;
    int row0 = blockIdx.x * 64 + wave * 16;
    int m = lane & 15, quad = lane >> 4;
    const half8* Bq = (const half8*)Wb;

    floatx4 acc[NCT];
#pragma unroll
    for (int c = 0; c < NCT; ++c) acc[c] = floatx4{0.f, 0.f, 0.f, 0.f};

    int ar = row0 + m;
    if (AF32 && ar > NNODES - 1) ar = NNODES - 1;   // clamp: x has exactly NNODES rows

#pragma unroll
    for (int ks = 0; ks < 4; ++ks) {
        half8 a;
        if constexpr (AF32) {
            const float* Af = (const float*)Av + (size_t)ar * 128 + quad * 8 + ks * 32;
            floatx4 f0 = *(const floatx4*)(Af);
            floatx4 f1 = *(const floatx4*)(Af + 4);
            a[0] = (_Float16)f0.x; a[1] = (_Float16)f0.y; a[2] = (_Float16)f0.z; a[3] = (_Float16)f0.w;
            a[4] = (_Float16)f1.x; a[5] = (_Float16)f1.y; a[6] = (_Float16)f1.z; a[7] = (_Float16)f1.w;
        } else {
            a = *(const half8*)((const __half*)Av + (size_t)(row0 + m) * 128 + quad * 8 + ks * 32);
        }
#pragma unroll
        for (int c = 0; c < NCT; ++c) {
            half8 b = Bq[(size_t)(ks * NCT + c) * 64 + lane];
            acc[c] = __builtin_amdgcn_mfma_f32_16x16x32_f16(a, b, acc[c], 0, 0, 0);
        }
    }

    if constexpr (!ZS32) {
        // stage all 2C=256 cols as f16: per-wave slab [16][264] (264: 16B-aligned rows)
        __shared__ _Float16 st[4][16][264];
#pragma unroll
        for (int c = 0; c < NCT; ++c) {
            bool is_self = (c < NCT / 2);
            int col = c * 16 + m;          // 0..255 (self: 0..127, neigh: 128..255)
            float bv = is_self ? bias[col] : 0.f;
#pragma unroll
            for (int r = 0; r < 4; ++r) st[wave][quad * 4 + r][col] = (_Float16)(acc[c][r] + bv);
        }
        // read back coalesced: 16 rows x 32 half8-chunks = 512, 8 passes
#pragma unroll
        for (int p = 0; p < 8; ++p) {
            int idx = p * 64 + lane;
            int row = idx >> 5, ch = idx & 31;
            int grow = row0 + row;
            half8 v = *(const half8*)&st[wave][row][ch * 8];
            if (ch < 16) {
                if (grow < NNODES)
                    *(half8*)((__half*)zs + (size_t)grow * C + ch * 8) = v;
            } else {
                if (grow < NNODES)
                    *(half8*)(zn + (size_t)grow * C + (ch - 16) * 8) = v;
                else if (grow == NNODES) {
                    half8 z;
#pragma unroll
                    for (int j = 0; j < 8; ++j) z[j] = (_Float16)0.f;
                    *(half8*)(zn + (size_t)grow * C + (ch - 16) * 8) = z;
                }
            }
        }
    } else {
        // C=64: zs f32 [16][68], zn f16 [16][72]
        __shared__ float    sts[4][16][68];
        __shared__ _Float16 stn[4][16][72];
#pragma unroll
        for (int c = 0; c < NCT; ++c) {
            bool is_self = (c < NCT / 2);
            int col = (is_self ? c : c - NCT / 2) * 16 + m;
            float bv = is_self ? bias[col] : 0.f;
#pragma unroll
            for (int r = 0; r < 4; ++r) {
                float v = acc[c][r] + bv;
                if (is_self) sts[wave][quad * 4 + r][col] = v;
                else         stn[wave][quad * 4 + r][col] = (_Float16)v;
            }
        }
        // zs: 16 rows x 16 float4 = 256, 4 passes
#pragma unroll
        for (int p = 0; p < 4; ++p) {
            int idx = p * 64 + lane;
            int row = idx >> 4, ch = idx & 15;
            int grow = row0 + row;
            if (grow < NNODES) {
                floatx4 v = *(const floatx4*)&sts[wave][row][ch * 4];
                *((floatx4*)zs + (size_t)grow * (C / 4) + ch) = v;
            }
        }
        // zn: 16 rows x 8 half8 = 128, 2 passes
#pragma unroll
        for (int p = 0; p < 2; ++p) {
            int idx = p * 64 + lane;
            int row = idx >> 3, ch = idx & 7;
            int grow = row0 + row;
            if (grow < NNODES) {
                half8 v = *(const half8*)&stn[wave][row][ch * 8];
                *(half8*)(zn + (size_t)grow * C + ch * 8) = v;
            } else if (grow == NNODES) {
                half8 z;
#pragma unroll
                for (int j = 0; j < 8; ++j) z[j] = (_Float16)0.f;
                *(half8*)(zn + (size_t)grow * C + ch * 8) = z;
            }
        }
    }
}

// ---------------- gather-add: subgroup-per-node (verbatim R8) ----------------
template <int C, bool RELU, bool ZS32>
__global__ __launch_bounds__(256) void k_aggadd(const __half* __restrict__ zn,
                                                const void* __restrict__ zs,
                                                const int* __restrict__ row_ptr,
                                                const int* __restrict__ edge_src,
                                                const float* __restrict__ deg_inv,
                                                void* __restrict__ outv) {
    constexpr int LPR  = C / 8;            // lanes per node-row: 16 (C=128) or 8
    constexpr int NSUB = 64 / LPR;         // nodes per wave: 4 or 8
    constexpr int NPB  = 4 * NSUB;         // nodes per block: 16 or 32
    int lane = threadIdx.x & 63;
    int su = lane / LPR;
    int lr = lane % LPR;
    int node = blockIdx.x * NPB + (threadIdx.x >> 6) * NSUB + su;
    unsigned rp = (unsigned)row_ptr[node];
    int beg = (int)(rp & 0xFFFFFFu);
    int nb  = (int)(rp >> 24);
    const half8* zb = (const half8*)zn;

    float s[8];
#pragma unroll
    for (int j = 0; j < 8; ++j) s[j] = 0.f;

    for (int b = 0; b < nb; ++b) {
        const int4v* ip = (const int4v*)(edge_src + beg + b * 16);
        int4v i0 = __builtin_nontemporal_load(ip);
        int4v i1 = __builtin_nontemporal_load(ip + 1);
        int4v i2 = __builtin_nontemporal_load(ip + 2);
        int4v i3 = __builtin_nontemporal_load(ip + 3);
        half8 v[16];
        v[0]  = zb[(size_t)i0.x * LPR + lr];
        v[1]  = zb[(size_t)i0.y * LPR + lr];
        v[2]  = zb[(size_t)i0.z * LPR + lr];
        v[3]  = zb[(size_t)i0.w * LPR + lr];
        v[4]  = zb[(size_t)i1.x * LPR + lr];
        v[5]  = zb[(size_t)i1.y * LPR + lr];
        v[6]  = zb[(size_t)i1.z * LPR + lr];
        v[7]  = zb[(size_t)i1.w * LPR + lr];
        v[8]  = zb[(size_t)i2.x * LPR + lr];
        v[9]  = zb[(size_t)i2.y * LPR + lr];
        v[10] = zb[(size_t)i2.z * LPR + lr];
        v[11] = zb[(size_t)i2.w * LPR + lr];
        v[12] = zb[(size_t)i3.x * LPR + lr];
        v[13] = zb[(size_t)i3.y * LPR + lr];
        v[14] = zb[(size_t)i3.z * LPR + lr];
        v[15] = zb[(size_t)i3.w * LPR + lr];
#pragma unroll
        for (int st = 1; st < 16; st <<= 1)
#pragma unroll
            for (int e = 0; e < 16; e += 2 * st) v[e] += v[e + st];
#pragma unroll
        for (int j = 0; j < 8; ++j) s[j] += (float)v[0][j];
    }

    float di = deg_inv[node];
    float o[8];
    if (ZS32) {
        const floatx4* zp = (const floatx4*)zs + (size_t)node * (C / 4) + lr * 2;
        floatx4 z0 = __builtin_nontemporal_load(zp);
        floatx4 z1 = __builtin_nontemporal_load(zp + 1);
        o[0] = z0.x + s[0] * di; o[1] = z0.y + s[1] * di;
        o[2] = z0.z + s[2] * di; o[3] = z0.w + s[3] * di;
        o[4] = z1.x + s[4] * di; o[5] = z1.y + s[5] * di;
        o[6] = z1.z + s[6] * di; o[7] = z1.w + s[7] * di;
    } else {
        half8 z = __builtin_nontemporal_load((const half8*)zs + (size_t)node * LPR + lr);
#pragma unroll
        for (int j = 0; j < 8; ++j) o[j] = (float)z[j] + s[j] * di;
    }
    if (RELU) {
#pragma unroll
        for (int j = 0; j < 8; ++j) o[j] = fmaxf(o[j], 0.f);
    }
    if (ZS32) {
        floatx4* op = (floatx4*)outv + (size_t)node * (C / 4) + lr * 2;
        __builtin_nontemporal_store(floatx4{o[0], o[1], o[2], o[3]}, op);
        __builtin_nontemporal_store(floatx4{o[4], o[5], o[6], o[7]}, op + 1);
    } else {
        half8 h;
#pragma unroll
        for (int j = 0; j < 8; ++j) h[j] = (_Float16)o[j];
        __builtin_nontemporal_store(h, (half8*)outv + (size_t)node * LPR + lr);
    }
}

// ---------------- launch ----------------

extern "C" void kernel_launch(void* const* d_in, const int* in_sizes, int n_in,
                              void* d_out, int out_size, void* d_ws, size_t ws_size,
                              hipStream_t stream) {
    const float* x   = (const float*)d_in[0];
    const int*   src = (const int*)d_in[1];
    const int*   dst = (const int*)d_in[2];
    const float* Ws0 = (const float*)d_in[3];
    const float* Wn0 = (const float*)d_in[4];
    const float* b0  = (const float*)d_in[5];
    const float* Ws1 = (const float*)d_in[6];
    const float* Wn1 = (const float*)d_in[7];
    const float* b1  = (const float*)d_in[8];
    const float* Ws2 = (const float*)d_in[9];
    const float* Wn2 = (const float*)d_in[10];
    const float* b2  = (const float*)d_in[11];
    float* out = (float*)d_out;

    char* ws = (char*)d_ws;
    size_t off = 0;
    auto alloc = [&](size_t bytes) -> void* {
        off = (off + 255) & ~(size_t)255;
        void* p = ws + off;
        off += bytes;
        return p;
    };
    int*      row_ptr  = (int*)alloc((size_t)NNODES * 4);
    float*    deg_inv  = (float*)alloc((size_t)NNODES * 4);
    int*      edge_src = (int*)alloc((size_t)NBKT * PCAP * 4);
    int*      gcur     = (int*)alloc((size_t)NBKT * 4);
    unsigned* pairs    = (unsigned*)alloc((size_t)NBKT * CAP * 4);
    __half*   h1       = (__half*)alloc((size_t)NPAD * 128 * 2);
    __half*   h2       = (__half*)alloc((size_t)NPAD * 128 * 2);
    __half*   zs16     = (__half*)alloc((size_t)NNODES * 128 * 2);
    __half*   zn128    = (__half*)alloc((size_t)NPAD * 128 * 2);
    float*    zs32     = (float*)alloc((size_t)NNODES * 64 * 4);
    __half*   zn64     = (__half*)alloc((size_t)NPAD * 64 * 2);
    __half*   Wb0      = (__half*)alloc((size_t)4 * 16 * 64 * 8 * 2);
    __half*   Wb1      = (__half*)alloc((size_t)4 * 16 * 64 * 8 * 2);
    __half*   Wb2      = (__half*)alloc((size_t)4 * 8 * 64 * 8 * 2);
    (void)ws_size; (void)n_in; (void)in_sizes; (void)out_size;

    // CSR build (bucketed, padded) + wshuf fused into binA's extra blocks
    hipMemsetAsync(gcur, 0, (size_t)NBKT * 4, stream);
    k_binA<<<NBLK_A + 40, 256, 0, stream>>>(src, dst, gcur, pairs,
                                            Ws0, Wn0, Wb0, Ws1, Wn1, Wb1, Ws2, Wn2, Wb2);
    k_binB<<<NBKT, 512, 0, stream>>>(pairs, gcur, row_ptr, deg_inv, edge_src);

    // layer 0: x (f32, converted in-kernel) -> h1
    k_gemm2<128, false, true><<<NBLK_GEMM, 256, 0, stream>>>(x, Wb0, b0, zs16, zn128);
    k_aggadd<128, true, false><<<NNODES / 16, 256, 0, stream>>>(zn128, zs16, row_ptr, edge_src, deg_inv, h1);
    // layer 1: h1 -> h2
    k_gemm2<128, false, false><<<NBLK_GEMM, 256, 0, stream>>>(h1, Wb1, b1, zs16, zn128);
    k_aggadd<128, true, false><<<NNODES / 16, 256, 0, stream>>>(zn128, zs16, row_ptr, edge_src, deg_inv, h2);
    // layer 2: h2 -> out (fp32), gather width 64
    k_gemm2<64, true, false><<<NBLK_GEMM, 256, 0, stream>>>(h2, Wb2, b2, zs32, zn64);
    k_aggadd<64, false, true><<<NNODES / 32, 256, 0, stream>>>(zn64, zs32, row_ptr, edge_src, deg_inv, out);
}

// Round 6
// 411.106 us; speedup vs baseline: 1.0862x; 1.0394x over previous
//
#include <hip/hip_runtime.h>
#include <hip/hip_fp16.h>

#define NNODES 100000
#define NPAD   100032            // 64*1563
#define NEDGES 1600000
#define NBLK_GEMM (NPAD / 64)    // 1563

#define BKT   512                // nodes per bucket
#define NBKT  ((NNODES + BKT - 1) / BKT)   // 196
#define CAP   10240              // real-edge slab capacity (mean 8192)
#define PCAP  18432              // padded slab capacity (CAP + 512*16)
#define EPB   2048               // edges per block, pass A
#define NBLK_A ((NEDGES + EPB - 1) / EPB)

typedef _Float16 half8 __attribute__((ext_vector_type(8)));
typedef float floatx4 __attribute__((ext_vector_type(4)));
typedef int int4v __attribute__((ext_vector_type(4)));

// ---------------- weight shuffle (f32 -> MFMA-B-layout f16) ------------------
template <int C>
__device__ inline void wshuf_one(const float* __restrict__ Ws, const float* __restrict__ Wn,
                                 __half* __restrict__ Wb, int t) {
    constexpr int NCT = 2 * C / 16;
    int lane  = t & 63;
    int ctile = (t >> 6) % NCT;
    int kstep = t / (64 * NCT);
    int n  = ctile * 16 + (lane & 15);
    int k0 = kstep * 32 + (lane >> 4) * 8;
    half8 w8;
#pragma unroll
    for (int j = 0; j < 8; ++j) {
        int k = k0 + j;
        float w = (n < C) ? Ws[k * C + n] : Wn[k * C + (n - C)];
        w8[j] = (_Float16)w;
    }
    ((half8*)Wb)[t] = w8;
}

// ---------------- CSR pass A + fused wshuf -----------------------------------
__global__ __launch_bounds__(256) void k_binA(const int* __restrict__ src, const int* __restrict__ dst,
                                              int* __restrict__ gcur, unsigned* __restrict__ pairs,
                                              const float* __restrict__ Ws0, const float* __restrict__ Wn0, __half* __restrict__ Wb0,
                                              const float* __restrict__ Ws1, const float* __restrict__ Wn1, __half* __restrict__ Wb1,
                                              const float* __restrict__ Ws2, const float* __restrict__ Wn2, __half* __restrict__ Wb2) {
    __shared__ int cnt[NBKT];
    __shared__ int cur[NBKT];
    if (blockIdx.x >= NBLK_A) {
        int wb = blockIdx.x - NBLK_A;
        if (wb < 16)      wshuf_one<128>(Ws0, Wn0, Wb0, wb * 256 + threadIdx.x);
        else if (wb < 32) wshuf_one<128>(Ws1, Wn1, Wb1, (wb - 16) * 256 + threadIdx.x);
        else              wshuf_one<64>(Ws2, Wn2, Wb2, (wb - 32) * 256 + threadIdx.x);
        return;
    }
    int t = threadIdx.x;
    if (t < NBKT) cnt[t] = 0;
    __syncthreads();
    int e0 = blockIdx.x * EPB;
    for (int i = t; i < EPB; i += 256) {
        int e = e0 + i;
        if (e < NEDGES) atomicAdd(&cnt[dst[e] >> 9], 1);
    }
    __syncthreads();
    if (t < NBKT) {
        int c = cnt[t];
        cur[t] = (c > 0) ? atomicAdd(&gcur[t], c) : 0;
    }
    __syncthreads();
    for (int i = t; i < EPB; i += 256) {
        int e = e0 + i;
        if (e < NEDGES) {
            int d = dst[e];
            int b = d >> 9;
            int pos = atomicAdd(&cur[b], 1);
            pairs[b * CAP + pos] = (unsigned)src[e] | ((unsigned)(d & 511) << 20);
        }
    }
}

// ---------------- CSR pass B body, 256 threads (2 nodes/thread) --------------
// R10: wave-level shfl_up scan (6 steps + 1 barrier) replaces the 18-barrier
// 512-wide Hillis-Steele; runs as blocks 0..NBKT-1 of the fused binB+gemm0
// kernel so the CSR finalize hides under layer-0's GEMM.
__device__ void binB_body(int b, const unsigned* __restrict__ pairs,
                          const int* __restrict__ gcnt,
                          int* __restrict__ row_ptr, float* __restrict__ deg_inv,
                          int* __restrict__ edge_src) {
    __shared__ int hist[BKT];
    __shared__ int woff[4];
    int t = threadIdx.x;               // 0..255
    int n = gcnt[b];
    int base = b * PCAP;
    const unsigned* pp = pairs + (size_t)b * CAP;
    hist[t] = 0; hist[t + 256] = 0;
    __syncthreads();
    for (int i = t; i < n; i += 256) atomicAdd(&hist[pp[i] >> 20], 1);
    __syncthreads();
    int v0 = hist[2 * t], v1 = hist[2 * t + 1];
    int p0 = (v0 + 15) & ~15, p1 = (v1 + 15) & ~15;
    int tsum = p0 + p1;
    // inclusive wave scan of tsum
    int lane = t & 63;
    int incl = tsum;
#pragma unroll
    for (int off = 1; off < 64; off <<= 1) {
        int u = __shfl_up(incl, off, 64);
        if (lane >= off) incl += u;
    }
    int w = t >> 6;
    if (lane == 63) woff[w] = incl;
    __syncthreads();
    int wo = 0;
#pragma unroll
    for (int i = 0; i < 4; ++i) wo += (i < w) ? woff[i] : 0;
    int excl = wo + incl - tsum;       // exclusive prefix of padded degs
    int pref0 = excl, pref1 = excl + p0;
    int node0 = b * BKT + 2 * t, node1 = node0 + 1;
    if (node0 < NNODES) {
        row_ptr[node0] = (base + pref0) | ((p0 >> 4) << 24);
        deg_inv[node0] = 1.0f / fmaxf((float)v0, 1.0f);
    }
    if (node1 < NNODES) {
        row_ptr[node1] = (base + pref1) | ((p1 >> 4) << 24);
        deg_inv[node1] = 1.0f / fmaxf((float)v1, 1.0f);
    }
    for (int i = v0; i < p0; ++i) edge_src[base + pref0 + i] = NNODES;
    for (int i = v1; i < p1; ++i) edge_src[base + pref1 + i] = NNODES;
    __syncthreads();
    hist[2 * t] = pref0; hist[2 * t + 1] = pref1;   // hist -> scatter cursors
    __syncthreads();
    for (int i = t; i < n; i += 256) {
        unsigned p = pp[i];
        int pos = atomicAdd(&hist[p >> 20], 1);
        edge_src[base + pos] = (int)(p & 0xFFFFF);
    }
}

// ---------------- MFMA GEMM body, LDS-staged coalesced epilogue --------------
template <int C, bool ZS32, bool AF32>
__device__ void gemm_body(int bid, const void* __restrict__ Av,
                          const __half* __restrict__ Wb,
                          const float* __restrict__ bias,
                          void* __restrict__ zs, __half* __restrict__ zn) {
    constexpr int NCT = 2 * C / 16;
    int lane = threadIdx.x & 63;
    int wave = threadIdx.x >> 6;
    int row0 = bid * 64 + wave * 16;
    int m = lane & 15, quad = lane >> 4;
    const half8* Bq = (const half8*)Wb;

    floatx4 acc[NCT];
#pragma unroll
    for (int c = 0; c < NCT; ++c) acc[c] = floatx4{0.f, 0.f, 0.f, 0.f};

    int ar = row0 + m;
    if (AF32 && ar > NNODES - 1) ar = NNODES - 1;   // clamp: x has exactly NNODES rows

#pragma unroll
    for (int ks = 0; ks < 4; ++ks) {
        half8 a;
        if constexpr (AF32) {
            const float* Af = (const float*)Av + (size_t)ar * 128 + quad * 8 + ks * 32;
            floatx4 f0 = *(const floatx4*)(Af);
            floatx4 f1 = *(const floatx4*)(Af + 4);
            a[0] = (_Float16)f0.x; a[1] = (_Float16)f0.y; a[2] = (_Float16)f0.z; a[3] = (_Float16)f0.w;
            a[4] = (_Float16)f1.x; a[5] = (_Float16)f1.y; a[6] = (_Float16)f1.z; a[7] = (_Float16)f1.w;
        } else {
            a = *(const half8*)((const __half*)Av + (size_t)(row0 + m) * 128 + quad * 8 + ks * 32);
        }
#pragma unroll
        for (int c = 0; c < NCT; ++c) {
            half8 b = Bq[(size_t)(ks * NCT + c) * 64 + lane];
            acc[c] = __builtin_amdgcn_mfma_f32_16x16x32_f16(a, b, acc[c], 0, 0, 0);
        }
    }

    if constexpr (!ZS32) {
        // stage all 2C=256 cols as f16: per-wave slab [16][264]
        __shared__ _Float16 st[4][16][264];
#pragma unroll
        for (int c = 0; c < NCT; ++c) {
            bool is_self = (c < NCT / 2);
            int col = c * 16 + m;          // 0..255 (self: 0..127, neigh: 128..255)
            float bv = is_self ? bias[col] : 0.f;
#pragma unroll
            for (int r = 0; r < 4; ++r) st[wave][quad * 4 + r][col] = (_Float16)(acc[c][r] + bv);
        }
#pragma unroll
        for (int p = 0; p < 8; ++p) {
            int idx = p * 64 + lane;
            int row = idx >> 5, ch = idx & 31;
            int grow = row0 + row;
            half8 v = *(const half8*)&st[wave][row][ch * 8];
            if (ch < 16) {
                if (grow < NNODES)
                    *(half8*)((__half*)zs + (size_t)grow * C + ch * 8) = v;
            } else {
                if (grow < NNODES)
                    *(half8*)(zn + (size_t)grow * C + (ch - 16) * 8) = v;
                else if (grow == NNODES) {
                    half8 z;
#pragma unroll
                    for (int j = 0; j < 8; ++j) z[j] = (_Float16)0.f;
                    *(half8*)(zn + (size_t)grow * C + (ch - 16) * 8) = z;
                }
            }
        }
    } else {
        // C=64: zs f32 [16][68], zn f16 [16][72]
        __shared__ float    sts[4][16][68];
        __shared__ _Float16 stn[4][16][72];
#pragma unroll
        for (int c = 0; c < NCT; ++c) {
            bool is_self = (c < NCT / 2);
            int col = (is_self ? c : c - NCT / 2) * 16 + m;
            float bv = is_self ? bias[col] : 0.f;
#pragma unroll
            for (int r = 0; r < 4; ++r) {
                float v = acc[c][r] + bv;
                if (is_self) sts[wave][quad * 4 + r][col] = v;
                else         stn[wave][quad * 4 + r][col] = (_Float16)v;
            }
        }
#pragma unroll
        for (int p = 0; p < 4; ++p) {
            int idx = p * 64 + lane;
            int row = idx >> 4, ch = idx & 15;
            int grow = row0 + row;
            if (grow < NNODES) {
                floatx4 v = *(const floatx4*)&sts[wave][row][ch * 4];
                *((floatx4*)zs + (size_t)grow * (C / 4) + ch) = v;
            }
        }
#pragma unroll
        for (int p = 0; p < 2; ++p) {
            int idx = p * 64 + lane;
            int row = idx >> 3, ch = idx & 7;
            int grow = row0 + row;
            if (grow < NNODES) {
                half8 v = *(const half8*)&stn[wave][row][ch * 8];
                *(half8*)(zn + (size_t)grow * C + ch * 8) = v;
            } else if (grow == NNODES) {
                half8 z;
#pragma unroll
                for (int j = 0; j < 8; ++j) z[j] = (_Float16)0.f;
                *(half8*)(zn + (size_t)grow * C + ch * 8) = z;
            }
        }
    }
}

// ---------------- fused: binB (blocks 0..NBKT-1) + layer-0 GEMM --------------
__global__ __launch_bounds__(256) void k_binBg0(const unsigned* __restrict__ pairs,
                                                const int* __restrict__ gcnt,
                                                int* __restrict__ row_ptr, float* __restrict__ deg_inv,
                                                int* __restrict__ edge_src,
                                                const float* __restrict__ x,
                                                const __half* __restrict__ Wb0,
                                                const float* __restrict__ b0,
                                                __half* __restrict__ zs16, __half* __restrict__ zn128) {
    if (blockIdx.x < NBKT) {
        binB_body(blockIdx.x, pairs, gcnt, row_ptr, deg_inv, edge_src);
        return;
    }
    gemm_body<128, false, true>(blockIdx.x - NBKT, x, Wb0, b0, zs16, zn128);
}

// ---------------- standalone GEMM (layers 1, 2) ------------------------------
template <int C, bool ZS32>
__global__ __launch_bounds__(256) void k_gemm2(const void* __restrict__ Av,
                                               const __half* __restrict__ Wb,
                                               const float* __restrict__ bias,
                                               void* __restrict__ zs,
                                               __half* __restrict__ zn) {
    gemm_body<C, ZS32, false>(blockIdx.x, Av, Wb, bias, zs, zn);
}

// ---------------- gather-add: subgroup-per-node (verbatim R8) ----------------
template <int C, bool RELU, bool ZS32>
__global__ __launch_bounds__(256) void k_aggadd(const __half* __restrict__ zn,
                                                const void* __restrict__ zs,
                                                const int* __restrict__ row_ptr,
                                                const int* __restrict__ edge_src,
                                                const float* __restrict__ deg_inv,
                                                void* __restrict__ outv) {
    constexpr int LPR  = C / 8;            // lanes per node-row: 16 (C=128) or 8
    constexpr int NSUB = 64 / LPR;         // nodes per wave: 4 or 8
    constexpr int NPB  = 4 * NSUB;         // nodes per block: 16 or 32
    int lane = threadIdx.x & 63;
    int su = lane / LPR;
    int lr = lane % LPR;
    int node = blockIdx.x * NPB + (threadIdx.x >> 6) * NSUB + su;
    unsigned rp = (unsigned)row_ptr[node];
    int beg = (int)(rp & 0xFFFFFFu);
    int nb  = (int)(rp >> 24);
    const half8* zb = (const half8*)zn;

    float s[8];
#pragma unroll
    for (int j = 0; j < 8; ++j) s[j] = 0.f;

    for (int b = 0; b < nb; ++b) {
        const int4v* ip = (const int4v*)(edge_src + beg + b * 16);
        int4v i0 = __builtin_nontemporal_load(ip);
        int4v i1 = __builtin_nontemporal_load(ip + 1);
        int4v i2 = __builtin_nontemporal_load(ip + 2);
        int4v i3 = __builtin_nontemporal_load(ip + 3);
        half8 v[16];
        v[0]  = zb[(size_t)i0.x * LPR + lr];
        v[1]  = zb[(size_t)i0.y * LPR + lr];
        v[2]  = zb[(size_t)i0.z * LPR + lr];
        v[3]  = zb[(size_t)i0.w * LPR + lr];
        v[4]  = zb[(size_t)i1.x * LPR + lr];
        v[5]  = zb[(size_t)i1.y * LPR + lr];
        v[6]  = zb[(size_t)i1.z * LPR + lr];
        v[7]  = zb[(size_t)i1.w * LPR + lr];
        v[8]  = zb[(size_t)i2.x * LPR + lr];
        v[9]  = zb[(size_t)i2.y * LPR + lr];
        v[10] = zb[(size_t)i2.z * LPR + lr];
        v[11] = zb[(size_t)i2.w * LPR + lr];
        v[12] = zb[(size_t)i3.x * LPR + lr];
        v[13] = zb[(size_t)i3.y * LPR + lr];
        v[14] = zb[(size_t)i3.z * LPR + lr];
        v[15] = zb[(size_t)i3.w * LPR + lr];
#pragma unroll
        for (int st = 1; st < 16; st <<= 1)
#pragma unroll
            for (int e = 0; e < 16; e += 2 * st) v[e] += v[e + st];
#pragma unroll
        for (int j = 0; j < 8; ++j) s[j] += (float)v[0][j];
    }

    float di = deg_inv[node];
    float o[8];
    if (ZS32) {
        const floatx4* zp = (const floatx4*)zs + (size_t)node * (C / 4) + lr * 2;
        floatx4 z0 = __builtin_nontemporal_load(zp);
        floatx4 z1 = __builtin_nontemporal_load(zp + 1);
        o[0] = z0.x + s[0] * di; o[1] = z0.y + s[1] * di;
        o[2] = z0.z + s[2] * di; o[3] = z0.w + s[3] * di;
        o[4] = z1.x + s[4] * di; o[5] = z1.y + s[5] * di;
        o[6] = z1.z + s[6] * di; o[7] = z1.w + s[7] * di;
    } else {
        half8 z = __builtin_nontemporal_load((const half8*)zs + (size_t)node * LPR + lr);
#pragma unroll
        for (int j = 0; j < 8; ++j) o[j] = (float)z[j] + s[j] * di;
    }
    if (RELU) {
#pragma unroll
        for (int j = 0; j < 8; ++j) o[j] = fmaxf(o[j], 0.f);
    }
    if (ZS32) {
        floatx4* op = (floatx4*)outv + (size_t)node * (C / 4) + lr * 2;
        __builtin_nontemporal_store(floatx4{o[0], o[1], o[2], o[3]}, op);
        __builtin_nontemporal_store(floatx4{o[4], o[5], o[6], o[7]}, op + 1);
    } else {
        half8 h;
#pragma unroll
        for (int j = 0; j < 8; ++j) h[j] = (_Float16)o[j];
        __builtin_nontemporal_store(h, (half8*)outv + (size_t)node * LPR + lr);
    }
}

// ---------------- launch ----------------

extern "C" void kernel_launch(void* const* d_in, const int* in_sizes, int n_in,
                              void* d_out, int out_size, void* d_ws, size_t ws_size,
                              hipStream_t stream) {
    const float* x   = (const float*)d_in[0];
    const int*   src = (const int*)d_in[1];
    const int*   dst = (const int*)d_in[2];
    const float* Ws0 = (const float*)d_in[3];
    const float* Wn0 = (const float*)d_in[4];
    const float* b0  = (const float*)d_in[5];
    const float* Ws1 = (const float*)d_in[6];
    const float* Wn1 = (const float*)d_in[7];
    const float* b1  = (const float*)d_in[8];
    const float* Ws2 = (const float*)d_in[9];
    const float* Wn2 = (const float*)d_in[10];
    const float* b2  = (const float*)d_in[11];
    float* out = (float*)d_out;

    char* ws = (char*)d_ws;
    size_t off = 0;
    auto alloc = [&](size_t bytes) -> void* {
        off = (off + 255) & ~(size_t)255;
        void* p = ws + off;
        off += bytes;
        return p;
    };
    int*      row_ptr  = (int*)alloc((size_t)NNODES * 4);
    float*    deg_inv  = (float*)alloc((size_t)NNODES * 4);
    int*      edge_src = (int*)alloc((size_t)NBKT * PCAP * 4);
    int*      gcur     = (int*)alloc((size_t)NBKT * 4);
    unsigned* pairs    = (unsigned*)alloc((size_t)NBKT * CAP * 4);
    __half*   h1       = (__half*)alloc((size_t)NPAD * 128 * 2);
    __half*   h2       = (__half*)alloc((size_t)NPAD * 128 * 2);
    __half*   zs16     = (__half*)alloc((size_t)NNODES * 128 * 2);
    __half*   zn128    = (__half*)alloc((size_t)NPAD * 128 * 2);
    float*    zs32     = (float*)alloc((size_t)NNODES * 64 * 4);
    __half*   zn64     = (__half*)alloc((size_t)NPAD * 64 * 2);
    __half*   Wb0      = (__half*)alloc((size_t)4 * 16 * 64 * 8 * 2);
    __half*   Wb1      = (__half*)alloc((size_t)4 * 16 * 64 * 8 * 2);
    __half*   Wb2      = (__half*)alloc((size_t)4 * 8 * 64 * 8 * 2);
    (void)ws_size; (void)n_in; (void)in_sizes; (void)out_size;

    // CSR pass A (+ wshuf in extra blocks)
    hipMemsetAsync(gcur, 0, (size_t)NBKT * 4, stream);
    k_binA<<<NBLK_A + 40, 256, 0, stream>>>(src, dst, gcur, pairs,
                                            Ws0, Wn0, Wb0, Ws1, Wn1, Wb1, Ws2, Wn2, Wb2);
    // CSR pass B fused with layer-0 GEMM (independent work, one dispatch)
    k_binBg0<<<NBKT + NBLK_GEMM, 256, 0, stream>>>(pairs, gcur, row_ptr, deg_inv, edge_src,
                                                   x, Wb0, b0, zs16, zn128);
    k_aggadd<128, true, false><<<NNODES / 16, 256, 0, stream>>>(zn128, zs16, row_ptr, edge_src, deg_inv, h1);
    // layer 1: h1 -> h2
    k_gemm2<128, false><<<NBLK_GEMM, 256, 0, stream>>>(h1, Wb1, b1, zs16, zn128);
    k_aggadd<128, true, false><<<NNODES / 16, 256, 0, stream>>>(zn128, zs16, row_ptr, edge_src, deg_inv, h2);
    // layer 2: h2 -> out (fp32), gather width 64
    k_gemm2<64, true><<<NBLK_GEMM, 256, 0, stream>>>(h2, Wb2, b2, zs32, zn64);
    k_aggadd<64, false, true><<<NNODES / 32, 256, 0, stream>>>(zn64, zs32, row_ptr, edge_src, deg_inv, out);
}

// Round 7
// 383.018 us; speedup vs baseline: 1.1659x; 1.0733x over previous
//
#include <hip/hip_runtime.h>
#include <hip/hip_fp16.h>

#define NNODES 100000
#define NPAD   100032            // 64*1563
#define NEDGES 1600000
#define NBLK_GEMM (NPAD / 64)    // 1563

#define BKT   512                // nodes per bucket
#define NBKT  ((NNODES + BKT - 1) / BKT)   // 196
#define CAP   10240              // real-edge slab capacity (mean 8192)
#define PCAP  18432              // padded slab capacity (CAP + 512*16)
#define EPB   2048               // edges per block, pass A
#define NBLK_A ((NEDGES + EPB - 1) / EPB)

typedef _Float16 half8 __attribute__((ext_vector_type(8)));
typedef float floatx4 __attribute__((ext_vector_type(4)));
typedef int int4v __attribute__((ext_vector_type(4)));

// ---------------- weight shuffle (f32 -> MFMA-B-layout f16) ------------------
template <int C>
__device__ inline void wshuf_one(const float* __restrict__ Ws, const float* __restrict__ Wn,
                                 __half* __restrict__ Wb, int t) {
    constexpr int NCT = 2 * C / 16;
    int lane  = t & 63;
    int ctile = (t >> 6) % NCT;
    int kstep = t / (64 * NCT);
    int n  = ctile * 16 + (lane & 15);
    int k0 = kstep * 32 + (lane >> 4) * 8;
    half8 w8;
#pragma unroll
    for (int j = 0; j < 8; ++j) {
        int k = k0 + j;
        float w = (n < C) ? Ws[k * C + n] : Wn[k * C + (n - C)];
        w8[j] = (_Float16)w;
    }
    ((half8*)Wb)[t] = w8;
}

// ---------------- CSR pass A + fused wshuf -----------------------------------
__global__ __launch_bounds__(256) void k_binA(const int* __restrict__ src, const int* __restrict__ dst,
                                              int* __restrict__ gcur, unsigned* __restrict__ pairs,
                                              const float* __restrict__ Ws0, const float* __restrict__ Wn0, __half* __restrict__ Wb0,
                                              const float* __restrict__ Ws1, const float* __restrict__ Wn1, __half* __restrict__ Wb1,
                                              const float* __restrict__ Ws2, const float* __restrict__ Wn2, __half* __restrict__ Wb2) {
    __shared__ int cnt[NBKT];
    __shared__ int cur[NBKT];
    if (blockIdx.x >= NBLK_A) {
        int wb = blockIdx.x - NBLK_A;
        if (wb < 16)      wshuf_one<128>(Ws0, Wn0, Wb0, wb * 256 + threadIdx.x);
        else if (wb < 32) wshuf_one<128>(Ws1, Wn1, Wb1, (wb - 16) * 256 + threadIdx.x);
        else              wshuf_one<64>(Ws2, Wn2, Wb2, (wb - 32) * 256 + threadIdx.x);
        return;
    }
    int t = threadIdx.x;
    if (t < NBKT) cnt[t] = 0;
    __syncthreads();
    int e0 = blockIdx.x * EPB;
    for (int i = t; i < EPB; i += 256) {
        int e = e0 + i;
        if (e < NEDGES) atomicAdd(&cnt[dst[e] >> 9], 1);
    }
    __syncthreads();
    if (t < NBKT) {
        int c = cnt[t];
        cur[t] = (c > 0) ? atomicAdd(&gcur[t], c) : 0;
    }
    __syncthreads();
    for (int i = t; i < EPB; i += 256) {
        int e = e0 + i;
        if (e < NEDGES) {
            int d = dst[e];
            int b = d >> 9;
            int pos = atomicAdd(&cur[b], 1);
            pairs[b * CAP + pos] = (unsigned)src[e] | ((unsigned)(d & 511) << 20);
        }
    }
}

// ---------------- CSR pass B body, 256 threads (2 nodes/thread) --------------
__device__ void binB_body(int b, const unsigned* __restrict__ pairs,
                          const int* __restrict__ gcnt,
                          int* __restrict__ row_ptr, float* __restrict__ deg_inv,
                          int* __restrict__ edge_src) {
    __shared__ int hist[BKT];
    __shared__ int woff[4];
    int t = threadIdx.x;               // 0..255
    int n = gcnt[b];
    int base = b * PCAP;
    const unsigned* pp = pairs + (size_t)b * CAP;
    hist[t] = 0; hist[t + 256] = 0;
    __syncthreads();
    for (int i = t; i < n; i += 256) atomicAdd(&hist[pp[i] >> 20], 1);
    __syncthreads();
    int v0 = hist[2 * t], v1 = hist[2 * t + 1];
    int p0 = (v0 + 15) & ~15, p1 = (v1 + 15) & ~15;
    int tsum = p0 + p1;
    int lane = t & 63;
    int incl = tsum;
#pragma unroll
    for (int off = 1; off < 64; off <<= 1) {
        int u = __shfl_up(incl, off, 64);
        if (lane >= off) incl += u;
    }
    int w = t >> 6;
    if (lane == 63) woff[w] = incl;
    __syncthreads();
    int wo = 0;
#pragma unroll
    for (int i = 0; i < 4; ++i) wo += (i < w) ? woff[i] : 0;
    int excl = wo + incl - tsum;       // exclusive prefix of padded degs
    int pref0 = excl, pref1 = excl + p0;
    int node0 = b * BKT + 2 * t, node1 = node0 + 1;
    if (node0 < NNODES) {
        row_ptr[node0] = (base + pref0) | ((p0 >> 4) << 24);
        deg_inv[node0] = 1.0f / fmaxf((float)v0, 1.0f);
    }
    if (node1 < NNODES) {
        row_ptr[node1] = (base + pref1) | ((p1 >> 4) << 24);
        deg_inv[node1] = 1.0f / fmaxf((float)v1, 1.0f);
    }
    for (int i = v0; i < p0; ++i) edge_src[base + pref0 + i] = NNODES;
    for (int i = v1; i < p1; ++i) edge_src[base + pref1 + i] = NNODES;
    __syncthreads();
    hist[2 * t] = pref0; hist[2 * t + 1] = pref1;   // hist -> scatter cursors
    __syncthreads();
    for (int i = t; i < n; i += 256) {
        unsigned p = pp[i];
        int pos = atomicAdd(&hist[p >> 20], 1);
        edge_src[base + pos] = (int)(p & 0xFFFFF);
    }
}

// ---------------- MFMA GEMM body (layer 0 only), LDS-staged epilogue ---------
__device__ void gemm0_body(int bid, const float* __restrict__ x,
                           const __half* __restrict__ Wb,
                           const float* __restrict__ bias,
                           __half* __restrict__ zs, __half* __restrict__ zn) {
    constexpr int NCT = 16;
    int lane = threadIdx.x & 63;
    int wave = threadIdx.x >> 6;
    int row0 = bid * 64 + wave * 16;
    int m = lane & 15, quad = lane >> 4;
    const half8* Bq = (const half8*)Wb;

    floatx4 acc[NCT];
#pragma unroll
    for (int c = 0; c < NCT; ++c) acc[c] = floatx4{0.f, 0.f, 0.f, 0.f};

    int ar = row0 + m;
    if (ar > NNODES - 1) ar = NNODES - 1;   // clamp: x has exactly NNODES rows

#pragma unroll
    for (int ks = 0; ks < 4; ++ks) {
        half8 a;
        const float* Af = x + (size_t)ar * 128 + quad * 8 + ks * 32;
        floatx4 f0 = *(const floatx4*)(Af);
        floatx4 f1 = *(const floatx4*)(Af + 4);
        a[0] = (_Float16)f0.x; a[1] = (_Float16)f0.y; a[2] = (_Float16)f0.z; a[3] = (_Float16)f0.w;
        a[4] = (_Float16)f1.x; a[5] = (_Float16)f1.y; a[6] = (_Float16)f1.z; a[7] = (_Float16)f1.w;
#pragma unroll
        for (int c = 0; c < NCT; ++c) {
            half8 b = Bq[(size_t)(ks * NCT + c) * 64 + lane];
            acc[c] = __builtin_amdgcn_mfma_f32_16x16x32_f16(a, b, acc[c], 0, 0, 0);
        }
    }

    // stage all 2C=256 cols as f16: per-wave slab [16][264]
    __shared__ _Float16 st[4][16][264];
#pragma unroll
    for (int c = 0; c < NCT; ++c) {
        bool is_self = (c < NCT / 2);
        int col = c * 16 + m;          // 0..255 (self: 0..127, neigh: 128..255)
        float bv = is_self ? bias[col] : 0.f;
#pragma unroll
        for (int r = 0; r < 4; ++r) st[wave][quad * 4 + r][col] = (_Float16)(acc[c][r] + bv);
    }
#pragma unroll
    for (int p = 0; p < 8; ++p) {
        int idx = p * 64 + lane;
        int row = idx >> 5, ch = idx & 31;
        int grow = row0 + row;
        half8 v = *(const half8*)&st[wave][row][ch * 8];
        if (ch < 16) {
            if (grow < NNODES)
                *(half8*)(zs + (size_t)grow * 128 + ch * 8) = v;
        } else {
            if (grow < NNODES)
                *(half8*)(zn + (size_t)grow * 128 + (ch - 16) * 8) = v;
            else if (grow == NNODES) {
                half8 z;
#pragma unroll
                for (int j = 0; j < 8; ++j) z[j] = (_Float16)0.f;
                *(half8*)(zn + (size_t)grow * 128 + (ch - 16) * 8) = z;
            }
        }
    }
}

// ---------------- fused: binB (blocks 0..NBKT-1) + layer-0 GEMM --------------
__global__ __launch_bounds__(256) void k_binBg0(const unsigned* __restrict__ pairs,
                                                const int* __restrict__ gcnt,
                                                int* __restrict__ row_ptr, float* __restrict__ deg_inv,
                                                int* __restrict__ edge_src,
                                                const float* __restrict__ x,
                                                const __half* __restrict__ Wb0,
                                                const float* __restrict__ b0,
                                                __half* __restrict__ zsA, __half* __restrict__ znA) {
    if (blockIdx.x < NBKT) {
        binB_body(blockIdx.x, pairs, gcnt, row_ptr, deg_inv, edge_src);
        return;
    }
    gemm0_body(blockIdx.x - NBKT, x, Wb0, b0, zsA, znA);
}

// ---------------- fused aggadd(layer L) + GEMM(layer L+1) --------------------
// R11: aggadd block = 16 nodes = exactly one 16-row MFMA A-tile. Agg phase
// drops relu(zs + agg*di) into LDS (no h1/h2 HBM roundtrip), then the 4 waves
// run the 16-row GEMM split by column-tiles (CPW ct each). zs/zn double-
// buffered across layers (agg reads layer-L zn while epilogue writes L+1).
template <int COUT>
__global__ __launch_bounds__(256) void k_aggemm(const __half* __restrict__ zn,
                                                const __half* __restrict__ zs,
                                                const int* __restrict__ row_ptr,
                                                const int* __restrict__ edge_src,
                                                const float* __restrict__ deg_inv,
                                                const __half* __restrict__ Wb,
                                                const float* __restrict__ bias,
                                                void* __restrict__ zs_out,
                                                __half* __restrict__ zn_out) {
    int t = threadIdx.x;
    int lane = t & 63, w = t >> 6;
    int su = lane >> 4, lr = lane & 15;
    int node = blockIdx.x * 16 + w * 4 + su;

    // zn_out sentinel row (read by the NEXT kernel's gather padding)
    if (blockIdx.x == 0 && t < COUT / 8) {
        half8 z;
#pragma unroll
        for (int j = 0; j < 8; ++j) z[j] = (_Float16)0.f;
        *(half8*)(zn_out + (size_t)NNODES * COUT + t * 8) = z;
    }

    // ---- agg phase (C_in = 128) ----
    unsigned rp = (unsigned)row_ptr[node];
    int beg = (int)(rp & 0xFFFFFFu);
    int nb  = (int)(rp >> 24);
    const half8* zb = (const half8*)zn;

    float s[8];
#pragma unroll
    for (int j = 0; j < 8; ++j) s[j] = 0.f;

    for (int b = 0; b < nb; ++b) {
        const int4v* ip = (const int4v*)(edge_src + beg + b * 16);
        int4v i0 = __builtin_nontemporal_load(ip);
        int4v i1 = __builtin_nontemporal_load(ip + 1);
        int4v i2 = __builtin_nontemporal_load(ip + 2);
        int4v i3 = __builtin_nontemporal_load(ip + 3);
        half8 v[16];
        v[0]  = zb[(size_t)i0.x * 16 + lr];
        v[1]  = zb[(size_t)i0.y * 16 + lr];
        v[2]  = zb[(size_t)i0.z * 16 + lr];
        v[3]  = zb[(size_t)i0.w * 16 + lr];
        v[4]  = zb[(size_t)i1.x * 16 + lr];
        v[5]  = zb[(size_t)i1.y * 16 + lr];
        v[6]  = zb[(size_t)i1.z * 16 + lr];
        v[7]  = zb[(size_t)i1.w * 16 + lr];
        v[8]  = zb[(size_t)i2.x * 16 + lr];
        v[9]  = zb[(size_t)i2.y * 16 + lr];
        v[10] = zb[(size_t)i2.z * 16 + lr];
        v[11] = zb[(size_t)i2.w * 16 + lr];
        v[12] = zb[(size_t)i3.x * 16 + lr];
        v[13] = zb[(size_t)i3.y * 16 + lr];
        v[14] = zb[(size_t)i3.z * 16 + lr];
        v[15] = zb[(size_t)i3.w * 16 + lr];
#pragma unroll
        for (int st = 1; st < 16; st <<= 1)
#pragma unroll
            for (int e = 0; e < 16; e += 2 * st) v[e] += v[e + st];
#pragma unroll
        for (int j = 0; j < 8; ++j) s[j] += (float)v[0][j];
    }

    float di = deg_inv[node];
    half8 z = __builtin_nontemporal_load((const half8*)zs + (size_t)node * 16 + lr);
    __shared__ _Float16 At[16][136];
    half8 h;
#pragma unroll
    for (int j = 0; j < 8; ++j) {
        float o = (float)z[j] + s[j] * di;
        h[j] = (_Float16)fmaxf(o, 0.f);          // ReLU (layers 0,1 both fused)
    }
    *(half8*)&At[w * 4 + su][lr * 8] = h;
    __syncthreads();

    // ---- gemm phase: 16 rows x 2*COUT cols, K=128 ----
    constexpr int NCT = 2 * COUT / 16;   // 16 (COUT=128) or 8 (COUT=64)
    constexpr int CPW = NCT / 4;         // ct per wave: 4 or 2
    int m = lane & 15, quad = lane >> 4;
    const half8* Bq = (const half8*)Wb;

    floatx4 acc[CPW];
#pragma unroll
    for (int cc = 0; cc < CPW; ++cc) acc[cc] = floatx4{0.f, 0.f, 0.f, 0.f};

#pragma unroll
    for (int ks = 0; ks < 4; ++ks) {
        half8 a = *(const half8*)&At[m][quad * 8 + ks * 32];
#pragma unroll
        for (int cc = 0; cc < CPW; ++cc) {
            int c = w * CPW + cc;
            half8 b = Bq[(size_t)(ks * NCT + c) * 64 + lane];
            acc[cc] = __builtin_amdgcn_mfma_f32_16x16x32_f16(a, b, acc[cc], 0, 0, 0);
        }
    }

    int grow0 = blockIdx.x * 16;         // all grow < NNODES (grid = NNODES/16)
    if constexpr (COUT == 128) {
        __shared__ _Float16 st2[16][264];
#pragma unroll
        for (int cc = 0; cc < CPW; ++cc) {
            int c = w * CPW + cc;
            bool is_self = (c < 8);
            int col = c * 16 + m;
            float bv = is_self ? bias[col] : 0.f;
#pragma unroll
            for (int r = 0; r < 4; ++r) st2[quad * 4 + r][col] = (_Float16)(acc[cc][r] + bv);
        }
        __syncthreads();
#pragma unroll
        for (int p = 0; p < 2; ++p) {
            int idx = p * 256 + t;
            int row = idx >> 5, ch = idx & 31;
            int grow = grow0 + row;
            half8 v = *(const half8*)&st2[row][ch * 8];
            if (ch < 16) *(half8*)((__half*)zs_out + (size_t)grow * 128 + ch * 8) = v;
            else         *(half8*)(zn_out + (size_t)grow * 128 + (ch - 16) * 8) = v;
        }
    } else {
        __shared__ float    sts[16][68];
        __shared__ _Float16 stn[16][72];
#pragma unroll
        for (int cc = 0; cc < CPW; ++cc) {
            int c = w * CPW + cc;
            bool is_self = (c < 4);
            if (is_self) {
                int col = c * 16 + m;
                float bv = bias[col];
#pragma unroll
                for (int r = 0; r < 4; ++r) sts[quad * 4 + r][col] = acc[cc][r] + bv;
            } else {
                int col = (c - 4) * 16 + m;
#pragma unroll
                for (int r = 0; r < 4; ++r) stn[quad * 4 + r][col] = (_Float16)acc[cc][r];
            }
        }
        __syncthreads();
        {
            int row = t >> 4, ch = t & 15;
            int grow = grow0 + row;
            *((floatx4*)zs_out + (size_t)grow * 16 + ch) = *(const floatx4*)&sts[row][ch * 4];
        }
        if (t < 128) {
            int row = t >> 3, ch = t & 7;
            int grow = grow0 + row;
            *(half8*)(zn_out + (size_t)grow * 64 + ch * 8) = *(const half8*)&stn[row][ch * 8];
        }
    }
}

// ---------------- final gather-add (layer 2, C=64, f32 out) ------------------
__global__ __launch_bounds__(256) void k_aggfin(const __half* __restrict__ zn,
                                                const float* __restrict__ zs,
                                                const int* __restrict__ row_ptr,
                                                const int* __restrict__ edge_src,
                                                const float* __restrict__ deg_inv,
                                                float* __restrict__ outv) {
    constexpr int LPR  = 8;              // lanes per node-row
    constexpr int NSUB = 8;              // nodes per wave
    constexpr int NPB  = 32;             // nodes per block
    int lane = threadIdx.x & 63;
    int su = lane / LPR;
    int lr = lane % LPR;
    int node = blockIdx.x * NPB + (threadIdx.x >> 6) * NSUB + su;
    unsigned rp = (unsigned)row_ptr[node];
    int beg = (int)(rp & 0xFFFFFFu);
    int nb  = (int)(rp >> 24);
    const half8* zb = (const half8*)zn;

    float s[8];
#pragma unroll
    for (int j = 0; j < 8; ++j) s[j] = 0.f;

    for (int b = 0; b < nb; ++b) {
        const int4v* ip = (const int4v*)(edge_src + beg + b * 16);
        int4v i0 = __builtin_nontemporal_load(ip);
        int4v i1 = __builtin_nontemporal_load(ip + 1);
        half8 v[16];
        v[0]  = zb[(size_t)i0.x * LPR + lr];
        v[1]  = zb[(size_t)i0.y * LPR + lr];
        v[2]  = zb[(size_t)i0.z * LPR + lr];
        v[3]  = zb[(size_t)i0.w * LPR + lr];
        v[4]  = zb[(size_t)i1.x * LPR + lr];
        v[5]  = zb[(size_t)i1.y * LPR + lr];
        v[6]  = zb[(size_t)i1.z * LPR + lr];
        v[7]  = zb[(size_t)i1.w * LPR + lr];
        const int4v* ip2 = ip + 2;
        int4v i2 = __builtin_nontemporal_load(ip2);
        int4v i3 = __builtin_nontemporal_load(ip2 + 1);
        v[8]  = zb[(size_t)i2.x * LPR + lr];
        v[9]  = zb[(size_t)i2.y * LPR + lr];
        v[10] = zb[(size_t)i2.z * LPR + lr];
        v[11] = zb[(size_t)i2.w * LPR + lr];
        v[12] = zb[(size_t)i3.x * LPR + lr];
        v[13] = zb[(size_t)i3.y * LPR + lr];
        v[14] = zb[(size_t)i3.z * LPR + lr];
        v[15] = zb[(size_t)i3.w * LPR + lr];
#pragma unroll
        for (int st = 1; st < 16; st <<= 1)
#pragma unroll
            for (int e = 0; e < 16; e += 2 * st) v[e] += v[e + st];
#pragma unroll
        for (int j = 0; j < 8; ++j) s[j] += (float)v[0][j];
    }

    float di = deg_inv[node];
    const floatx4* zp = (const floatx4*)zs + (size_t)node * 16 + lr * 2;
    floatx4 z0 = __builtin_nontemporal_load(zp);
    floatx4 z1 = __builtin_nontemporal_load(zp + 1);
    float o[8];
    o[0] = z0.x + s[0] * di; o[1] = z0.y + s[1] * di;
    o[2] = z0.z + s[2] * di; o[3] = z0.w + s[3] * di;
    o[4] = z1.x + s[4] * di; o[5] = z1.y + s[5] * di;
    o[6] = z1.z + s[6] * di; o[7] = z1.w + s[7] * di;
    floatx4* op = (floatx4*)outv + (size_t)node * 16 + lr * 2;
    __builtin_nontemporal_store(floatx4{o[0], o[1], o[2], o[3]}, op);
    __builtin_nontemporal_store(floatx4{o[4], o[5], o[6], o[7]}, op + 1);
}

// ---------------- launch ----------------

extern "C" void kernel_launch(void* const* d_in, const int* in_sizes, int n_in,
                              void* d_out, int out_size, void* d_ws, size_t ws_size,
                              hipStream_t stream) {
    const float* x   = (const float*)d_in[0];
    const int*   src = (const int*)d_in[1];
    const int*   dst = (const int*)d_in[2];
    const float* Ws0 = (const float*)d_in[3];
    const float* Wn0 = (const float*)d_in[4];
    const float* b0  = (const float*)d_in[5];
    const float* Ws1 = (const float*)d_in[6];
    const float* Wn1 = (const float*)d_in[7];
    const float* b1  = (const float*)d_in[8];
    const float* Ws2 = (const float*)d_in[9];
    const float* Wn2 = (const float*)d_in[10];
    const float* b2  = (const float*)d_in[11];
    float* out = (float*)d_out;

    char* ws = (char*)d_ws;
    size_t off = 0;
    auto alloc = [&](size_t bytes) -> void* {
        off = (off + 255) & ~(size_t)255;
        void* p = ws + off;
        off += bytes;
        return p;
    };
    int*      row_ptr  = (int*)alloc((size_t)NNODES * 4);
    float*    deg_inv  = (float*)alloc((size_t)NNODES * 4);
    int*      edge_src = (int*)alloc((size_t)NBKT * PCAP * 4);
    int*      gcur     = (int*)alloc((size_t)NBKT * 4);
    unsigned* pairs    = (unsigned*)alloc((size_t)NBKT * CAP * 4);
    __half*   zsA      = (__half*)alloc((size_t)NPAD * 128 * 2);
    __half*   znA      = (__half*)alloc((size_t)NPAD * 128 * 2);
    __half*   zsB      = (__half*)alloc((size_t)NPAD * 128 * 2);
    __half*   znB      = (__half*)alloc((size_t)NPAD * 128 * 2);
    float*    zs32     = (float*)alloc((size_t)NNODES * 64 * 4);
    __half*   zn64     = (__half*)alloc((size_t)NPAD * 64 * 2);
    __half*   Wb0      = (__half*)alloc((size_t)4 * 16 * 64 * 8 * 2);
    __half*   Wb1      = (__half*)alloc((size_t)4 * 16 * 64 * 8 * 2);
    __half*   Wb2      = (__half*)alloc((size_t)4 * 8 * 64 * 8 * 2);
    (void)ws_size; (void)n_in; (void)in_sizes; (void)out_size;

    // CSR pass A (+ wshuf in extra blocks)
    hipMemsetAsync(gcur, 0, (size_t)NBKT * 4, stream);
    k_binA<<<NBLK_A + 40, 256, 0, stream>>>(src, dst, gcur, pairs,
                                            Ws0, Wn0, Wb0, Ws1, Wn1, Wb1, Ws2, Wn2, Wb2);
    // CSR pass B fused with layer-0 GEMM
    k_binBg0<<<NBKT + NBLK_GEMM, 256, 0, stream>>>(pairs, gcur, row_ptr, deg_inv, edge_src,
                                                   x, Wb0, b0, zsA, znA);
    // agg layer 0 + GEMM layer 1 (fused; no h1 roundtrip)
    k_aggemm<128><<<NNODES / 16, 256, 0, stream>>>(znA, zsA, row_ptr, edge_src, deg_inv,
                                                   Wb1, b1, zsB, znB);
    // agg layer 1 + GEMM layer 2 (fused; no h2 roundtrip)
    k_aggemm<64><<<NNODES / 16, 256, 0, stream>>>(znB, zsB, row_ptr, edge_src, deg_inv,
                                                  Wb2, b2, zs32, zn64);
    // final agg layer 2 -> out (f32)
    k_aggfin<<<NNODES / 32, 256, 0, stream>>>(zn64, zs32, row_ptr, edge_src, deg_inv, out);
}